// Round 6
// baseline (6208.244 us; speedup 1.0000x reference)
//
#include <hip/hip_runtime.h>
#include <math.h>

// LSTM B=512 T=1000 I=64 H=50. Split design:
//  K0: WT[i][g] = W_ih[g][i] (tiny transpose)
//  K1: xg[m][g] = x[m][:]·W_ih[g][:] + b_ih[g] + b_hh[g]
//      LDS-staged WT (53KB) + x-tile (17KB); thread ni owns column ni,
//      acc[8] per 8-row subtile (small reg state -> no demotion);
//      w reads lane-consecutive (conflict-free), x reads wave-uniform
//      broadcast b128; stores coalesced.
//  K2: recurrence, quad mapping: lane-quad holds gates i,f,g,o of unit j.
//      Full 50-FMA dot per lane (weights asm-pinned, 13 regs), gates
//      combine via intra-quad __shfl, c redundant per quad, ONE barrier
//      per step (round-5 had two + gs[] LDS round trip).
// Fallback (ws too small): round-1 fused kernel (proven).

#define HSZ 50
#define ISZ 64
#define TSZ 1000
#define GSZ 200
#define K1_TM 64   // K1 rows per block

typedef float float4v __attribute__((ext_vector_type(4)));
typedef float float2v __attribute__((ext_vector_type(2)));

// ---------------- K0: transpose W_ih -> WT[64][200] ----------------
__global__ void wt_transpose(const float* __restrict__ W_ih,
                             float* __restrict__ WT) {
    int j = blockIdx.x * 256 + threadIdx.x;       // 12800 elems
    if (j < 12800) {
        int i = j / 200, g = j % 200;
        WT[j] = W_ih[g * 64 + i];
    }
}

// ---------------- K1: xg GEMM ----------------
__global__ __launch_bounds__(256, 2) void xg_gemm(
    const float* __restrict__ x,      // [M][64]
    const float* __restrict__ WT,     // [64][200]
    const float* __restrict__ b_ih,
    const float* __restrict__ b_hh,
    float* __restrict__ xg,           // [M][200]
    int M)
{
    __shared__ float wt_lds[64 * 208];     // 53.2 KB, 208 pad
    __shared__ float x_lds[K1_TM * 68];    // 17.4 KB, 68 pad (b128-aligned)
    const int tid = threadIdx.x;
    const long long m0 = (long long)blockIdx.x * K1_TM;

    // stage WT: 12800 floats, coalesced reads, near-consecutive LDS writes
    for (int p = 0; p < 50; ++p) {
        int f = tid + p * 256;             // 0..12799
        int k = f / 200, n = f % 200;
        wt_lds[k * 208 + n] = WT[f];
    }
    // stage x tile: 64 rows x 16 float4
    const float4* x4 = (const float4*)x;
    #pragma unroll
    for (int p = 0; p < 4; ++p) {
        int f4 = tid + p * 256;            // 0..1023
        int row = f4 >> 4, c4 = f4 & 15;
        long long mm = m0 + row;
        float4 v = x4[(mm < M ? mm : 0) * 16 + c4];
        *(float4*)&x_lds[row * 68 + c4 * 4] = v;
    }
    __syncthreads();

    const int ni = (tid < GSZ) ? tid : (GSZ - 1);
    const float bias = b_ih[ni] + b_hh[ni];

    #pragma unroll 1
    for (int s = 0; s < K1_TM / 8; ++s) {
        float acc[8];
        #pragma unroll
        for (int r = 0; r < 8; ++r) acc[r] = 0.0f;
        #pragma unroll
        for (int k = 0; k < 64; k += 4) {
            const float w0 = wt_lds[(k + 0) * 208 + ni];
            const float w1 = wt_lds[(k + 1) * 208 + ni];
            const float w2 = wt_lds[(k + 2) * 208 + ni];
            const float w3 = wt_lds[(k + 3) * 208 + ni];
            #pragma unroll
            for (int r = 0; r < 8; ++r) {
                const float4 xv = *(const float4*)&x_lds[(s * 8 + r) * 68 + k];
                acc[r] = fmaf(xv.w, w3, fmaf(xv.z, w2,
                         fmaf(xv.y, w1, fmaf(xv.x, w0, acc[r]))));
            }
        }
        if (tid < GSZ) {
            #pragma unroll
            for (int r = 0; r < 8; ++r) {
                long long mm = m0 + s * 8 + r;
                if (mm < M) xg[mm * GSZ + ni] = acc[r] + bias;
            }
        }
    }
}

// ---------------- K2: recurrence ----------------
#define LD4(dst, base, OFS) \
    asm volatile("global_load_dwordx4 %0, %1, off offset:" OFS \
                 : "=v"(dst) : "v"(base))
#define LD2(dst, base, OFS) \
    asm volatile("global_load_dwordx2 %0, %1, off offset:" OFS \
                 : "=v"(dst) : "v"(base))

__global__ __launch_bounds__(256, 2) void lstm_rec(
    const float* __restrict__ xg,     // [M][200] biases folded
    const float* __restrict__ W_hh,   // [200][50]
    const float* __restrict__ W_out,
    const float* __restrict__ b_out,
    float* __restrict__ out)
{
    const int b   = blockIdx.x;
    const int tid = threadIdx.x;
    const int l   = tid & 63;                 // wave lane
    const int qb  = l & ~3;                   // quad base (wave-relative)
    const int j   = (tid < GSZ) ? (tid >> 2) : (HSZ - 1);
    const int cls = (tid < GSZ) ? (tid & 3)  : 3;   // 0=i 1=f 2=g 3=o
    const int G   = cls * HSZ + j;            // gate row

    __shared__ __align__(16) float hs[2][56];

    // W_hh row pinned: 13 regs = 52 floats
    const float* whb = W_hh + (size_t)G * HSZ;
    float4v wh0, wh1, wh2, wh3, wh4, wh5, wh6, wh7, wh8, wh9, wh10, wh11;
    float2v whc;
    LD4(wh0, whb, "0");   LD4(wh1, whb, "16");  LD4(wh2,  whb, "32");
    LD4(wh3, whb, "48");  LD4(wh4, whb, "64");  LD4(wh5,  whb, "80");
    LD4(wh6, whb, "96");  LD4(wh7, whb, "112"); LD4(wh8,  whb, "128");
    LD4(wh9, whb, "144"); LD4(wh10, whb, "160"); LD4(wh11, whb, "176");
    LD2(whc, whb, "192");
    asm volatile("s_waitcnt vmcnt(0)"
        : "+v"(wh0), "+v"(wh1), "+v"(wh2), "+v"(wh3), "+v"(wh4), "+v"(wh5),
          "+v"(wh6), "+v"(wh7), "+v"(wh8), "+v"(wh9), "+v"(wh10), "+v"(wh11),
          "+v"(whc)
        :: "memory");

    const float s1 = (cls == 2) ? 2.0f : 1.0f;
    const float s2 = s1;
    const float s3 = (cls == 2) ? -1.0f : 0.0f;

    float c_reg = 0.0f;
    if (tid < 56) { hs[0][tid] = 0.0f; hs[1][tid] = 0.0f; }

    const float* xgb = xg + (long long)b * TSZ * GSZ + G;

    // 4-deep prefetch ring
    float p0 = xgb[0 * GSZ], p1 = xgb[1 * GSZ],
          p2 = xgb[2 * GSZ], p3 = xgb[3 * GSZ];
    __syncthreads();

#define STEP(P, T) {                                                        \
        float a0 = (P), a1 = 0.0f, a2 = 0.0f, a3 = 0.0f;                    \
        {   int tp = (T) + 4; if (tp > TSZ - 1) tp = 0;                     \
            (P) = xgb[tp * GSZ]; }                                          \
        const float* hrow = &hs[(T) & 1][0];                                \
        const float4v* h4 = (const float4v*)hrow;                           \
        { float4v v = h4[0];  a0 = fmaf(v.x, wh0.x, a0);  a1 = fmaf(v.y, wh0.y, a1);  a2 = fmaf(v.z, wh0.z, a2);  a3 = fmaf(v.w, wh0.w, a3); } \
        { float4v v = h4[1];  a0 = fmaf(v.x, wh1.x, a0);  a1 = fmaf(v.y, wh1.y, a1);  a2 = fmaf(v.z, wh1.z, a2);  a3 = fmaf(v.w, wh1.w, a3); } \
        { float4v v = h4[2];  a0 = fmaf(v.x, wh2.x, a0);  a1 = fmaf(v.y, wh2.y, a1);  a2 = fmaf(v.z, wh2.z, a2);  a3 = fmaf(v.w, wh2.w, a3); } \
        { float4v v = h4[3];  a0 = fmaf(v.x, wh3.x, a0);  a1 = fmaf(v.y, wh3.y, a1);  a2 = fmaf(v.z, wh3.z, a2);  a3 = fmaf(v.w, wh3.w, a3); } \
        { float4v v = h4[4];  a0 = fmaf(v.x, wh4.x, a0);  a1 = fmaf(v.y, wh4.y, a1);  a2 = fmaf(v.z, wh4.z, a2);  a3 = fmaf(v.w, wh4.w, a3); } \
        { float4v v = h4[5];  a0 = fmaf(v.x, wh5.x, a0);  a1 = fmaf(v.y, wh5.y, a1);  a2 = fmaf(v.z, wh5.z, a2);  a3 = fmaf(v.w, wh5.w, a3); } \
        { float4v v = h4[6];  a0 = fmaf(v.x, wh6.x, a0);  a1 = fmaf(v.y, wh6.y, a1);  a2 = fmaf(v.z, wh6.z, a2);  a3 = fmaf(v.w, wh6.w, a3); } \
        { float4v v = h4[7];  a0 = fmaf(v.x, wh7.x, a0);  a1 = fmaf(v.y, wh7.y, a1);  a2 = fmaf(v.z, wh7.z, a2);  a3 = fmaf(v.w, wh7.w, a3); } \
        { float4v v = h4[8];  a0 = fmaf(v.x, wh8.x, a0);  a1 = fmaf(v.y, wh8.y, a1);  a2 = fmaf(v.z, wh8.z, a2);  a3 = fmaf(v.w, wh8.w, a3); } \
        { float4v v = h4[9];  a0 = fmaf(v.x, wh9.x, a0);  a1 = fmaf(v.y, wh9.y, a1);  a2 = fmaf(v.z, wh9.z, a2);  a3 = fmaf(v.w, wh9.w, a3); } \
        { float4v v = h4[10]; a0 = fmaf(v.x, wh10.x, a0); a1 = fmaf(v.y, wh10.y, a1); a2 = fmaf(v.z, wh10.z, a2); a3 = fmaf(v.w, wh10.w, a3); } \
        { float4v v = h4[11]; a0 = fmaf(v.x, wh11.x, a0); a1 = fmaf(v.y, wh11.y, a1); a2 = fmaf(v.z, wh11.z, a2); a3 = fmaf(v.w, wh11.w, a3); } \
        { float2v v = *(const float2v*)(hrow + 48);                         \
          a0 = fmaf(v.x, whc.x, a0); a1 = fmaf(v.y, whc.y, a1); }           \
        const float accv = (a0 + a1) + (a2 + a3);                           \
        const float sig  = 1.0f / (1.0f + __expf(-s1 * accv));              \
        const float act  = fmaf(s2, sig, s3);                               \
        const float gi = __shfl(act, qb + 0);                               \
        const float gf = __shfl(act, qb + 1);                               \
        const float gg = __shfl(act, qb + 2);                               \
        const float go = __shfl(act, qb + 3);                               \
        c_reg = fmaf(gf, c_reg, gi * gg);                                   \
        const float tc = fmaf(2.0f, 1.0f / (1.0f + __expf(-2.0f * c_reg)), -1.0f); \
        if (cls == 0) hs[((T) + 1) & 1][j] = go * tc;                       \
        __syncthreads(); }

    for (int t = 0; t < TSZ; t += 4) {
        STEP(p0, t)
        STEP(p1, t + 1)
        STEP(p2, t + 2)
        STEP(p3, t + 3)
    }
#undef STEP

    if (tid < 2) {
        float acc = b_out[tid];
        const float* wo = W_out + tid * HSZ;
        const float* hf = &hs[0][0];              // 1000 & 1 == 0
        #pragma unroll
        for (int jj = 0; jj < HSZ; ++jj) acc = fmaf(hf[jj], wo[jj], acc);
        out[b * 2 + tid] = acc;
    }
}

// ---------------- Fallback: round-1 fused kernel (proven) ----------------
__global__ __launch_bounds__(256, 2) void lstm_fallback(
    const float* __restrict__ x, const float* __restrict__ W_ih,
    const float* __restrict__ W_hh, const float* __restrict__ b_ih,
    const float* __restrict__ b_hh, const float* __restrict__ W_out,
    const float* __restrict__ b_out, float* __restrict__ out)
{
    const int b = blockIdx.x, tid = threadIdx.x;
    __shared__ __align__(16) float xs[2][ISZ];
    __shared__ __align__(16) float hs[HSZ + 2];
    __shared__ __align__(16) float gs[GSZ];
    float wih[ISZ]; float whh[HSZ]; float bias = 0.0f;
    if (tid < GSZ) {
        const float* wi = W_ih + tid * ISZ;
        #pragma unroll
        for (int i = 0; i < ISZ; ++i) wih[i] = wi[i];
        const float* wh = W_hh + tid * HSZ;
        #pragma unroll
        for (int j = 0; j < HSZ; ++j) whh[j] = wh[j];
        bias = b_ih[tid] + b_hh[tid];
    }
    float c_reg = 0.0f;
    if (tid < HSZ) hs[tid] = 0.0f;
    const float* xb = x + (size_t)b * (TSZ * ISZ);
    if (tid < ISZ) xs[0][tid] = xb[tid];
    __syncthreads();
    for (int t = 0; t < TSZ; ++t) {
        const int cur = t & 1, nxt = cur ^ 1;
        float xpre = 0.0f;
        const bool pf = (t + 1 < TSZ) && (tid < ISZ);
        if (pf) xpre = xb[(size_t)(t + 1) * ISZ + tid];
        if (tid < GSZ) {
            float acc = bias;
            const float4* x4 = (const float4*)(&xs[cur][0]);
            #pragma unroll
            for (int i = 0; i < ISZ / 4; ++i) {
                float4 v = x4[i];
                acc += v.x * wih[4*i] + v.y * wih[4*i+1] + v.z * wih[4*i+2] + v.w * wih[4*i+3];
            }
            const float4* h4 = (const float4*)(&hs[0]);
            #pragma unroll
            for (int j = 0; j < 12; ++j) {
                float4 v = h4[j];
                acc += v.x * whh[4*j] + v.y * whh[4*j+1] + v.z * whh[4*j+2] + v.w * whh[4*j+3];
            }
            acc += hs[48] * whh[48] + hs[49] * whh[49];
            float a = (tid >= 2*HSZ && tid < 3*HSZ)
                ? (1.0f - 2.0f / (1.0f + __expf(2.0f * acc)))
                : (1.0f / (1.0f + __expf(-acc)));
            gs[tid] = a;
        }
        if (pf) xs[nxt][tid] = xpre;
        __syncthreads();
        if (tid < HSZ) {
            float ig = gs[tid], fg = gs[tid+HSZ], gg = gs[tid+2*HSZ], og = gs[tid+3*HSZ];
            c_reg = fg * c_reg + ig * gg;
            hs[tid] = og * (1.0f - 2.0f / (1.0f + __expf(2.0f * c_reg)));
        }
        __syncthreads();
    }
    if (tid < 2) {
        float acc = b_out[tid];
        const float* wo = W_out + tid * HSZ;
        #pragma unroll
        for (int j = 0; j < HSZ; ++j) acc = fmaf(hs[j], wo[j], acc);
        out[b * 2 + tid] = acc;
    }
}

extern "C" void kernel_launch(void* const* d_in, const int* in_sizes, int n_in,
                              void* d_out, int out_size, void* d_ws, size_t ws_size,
                              hipStream_t stream) {
    const float* x     = (const float*)d_in[0];
    const float* W_ih  = (const float*)d_in[1];
    const float* W_hh  = (const float*)d_in[2];
    const float* b_ih  = (const float*)d_in[3];
    const float* b_hh  = (const float*)d_in[4];
    const float* W_out = (const float*)d_in[5];
    const float* b_out = (const float*)d_in[6];
    float* out = (float*)d_out;

    const int B = in_sizes[0] / (TSZ * ISZ);        // 512
    const int M = B * TSZ;                          // 512000
    const size_t xg_bytes = (size_t)M * GSZ * 4;    // 409.6 MB
    const size_t need = xg_bytes + 12800 * 4;       // + WT

    if (ws_size >= need) {
        float* xg = (float*)d_ws;
        float* WT = (float*)((char*)d_ws + xg_bytes);
        hipLaunchKernelGGL(wt_transpose, dim3(50), dim3(256), 0, stream, W_ih, WT);
        const int nblk = (M + K1_TM - 1) / K1_TM;
        hipLaunchKernelGGL(xg_gemm, dim3(nblk), dim3(256), 0, stream,
                           x, WT, b_ih, b_hh, xg, M);
        hipLaunchKernelGGL(lstm_rec, dim3(B), dim3(256), 0, stream,
                           xg, W_hh, W_out, b_out, out);
    } else {
        hipLaunchKernelGGL(lstm_fallback, dim3(B), dim3(256), 0, stream,
                           x, W_ih, W_hh, b_ih, b_hh, W_out, b_out, out);
    }
}